// Round 8
// baseline (720.311 us; speedup 1.0000x reference)
//
#include <hip/hip_runtime.h>

#define BN 1000000
#define KN 16384
#define HN 64
#define TPB 256
#define NW  4
#define NBLK 512                      // persistent grid: 2 blocks/CU guaranteed co-resident
#define NCHUNK ((BN + TPB - 1) / TPB) // 3907

typedef __bf16 bf16x8 __attribute__((ext_vector_type(8)));
typedef float  f32x4  __attribute__((ext_vector_type(4)));
typedef unsigned short u16x8 __attribute__((ext_vector_type(8)));

__device__ __forceinline__ unsigned short f2bf(float f) {
    return __builtin_bit_cast(unsigned short, (__bf16)f);   // HW v_cvt (RTNE), ~1 op
}
__device__ __forceinline__ float bf2f(unsigned short b) {
    return (float)__builtin_bit_cast(__bf16, b);
}
__device__ __forceinline__ float silu_f(float v) {
    return v * __builtin_amdgcn_rcpf(1.0f + __expf(-v));
}
__device__ __forceinline__ f32x4 mfma16(bf16x8 a, bf16x8 b, f32x4 c) {
    return __builtin_amdgcn_mfma_f32_16x16x32_bf16(a, b, c, 0, 0, 0);
}

// ---- XLA ErfInv32 polynomial ----
__device__ __forceinline__ float erfinv_xla(float x) {
    float w = -log1pf(-x * x);
    float p;
    if (w < 5.0f) {
        w -= 2.5f;
        p = 2.81022636e-08f;
        p = fmaf(p, w, 3.43273939e-07f);
        p = fmaf(p, w, -3.5233877e-06f);
        p = fmaf(p, w, -4.39150654e-06f);
        p = fmaf(p, w, 0.00021858087f);
        p = fmaf(p, w, -0.00125372503f);
        p = fmaf(p, w, -0.00417768164f);
        p = fmaf(p, w, 0.246640727f);
        p = fmaf(p, w, 1.50140941f);
    } else {
        w = sqrtf(w) - 3.0f;
        p = -0.000200214257f;
        p = fmaf(p, w, 0.000100950558f);
        p = fmaf(p, w, 0.00134934322f);
        p = fmaf(p, w, -0.00367342844f);
        p = fmaf(p, w, 0.00573950773f);
        p = fmaf(p, w, -0.0076224613f);
        p = fmaf(p, w, 0.00943887047f);
        p = fmaf(p, w, 1.00167406f);
        p = fmaf(p, w, 2.83297682f);
    }
    return p * x;
}

// ---- jax.random.normal(key(42), (16384,)), threefry_partitionable: bits = out0^out1 ----
__device__ __forceinline__ float jax_eps16384(int gid) {
    const unsigned k0 = 0u, k1 = 42u, k2 = 0x1BD11BDAu ^ 0u ^ 42u;
    unsigned x0 = 0u + k0;
    unsigned x1 = (unsigned)gid + k1;
#define TF_RND(r) { x0 += x1; x1 = (x1 << (r)) | (x1 >> (32 - (r))); x1 ^= x0; }
    TF_RND(13) TF_RND(15) TF_RND(26) TF_RND(6)  x0 += k1; x1 += k2 + 1u;
    TF_RND(17) TF_RND(29) TF_RND(16) TF_RND(24) x0 += k2; x1 += k0 + 2u;
    TF_RND(13) TF_RND(15) TF_RND(26) TF_RND(6)  x0 += k0; x1 += k1 + 3u;
    TF_RND(17) TF_RND(29) TF_RND(16) TF_RND(24) x0 += k1; x1 += k2 + 4u;
    TF_RND(13) TF_RND(15) TF_RND(26) TF_RND(6)  x0 += k2; x1 += k0 + 5u;
#undef TF_RND
    unsigned bits = x0 ^ x1;
    float f = __uint_as_float((bits >> 9) | 0x3f800000u) - 1.0f;
    const float mn = -0.99999994f;
    float u = fmaxf(f * 2.0f + mn, mn);
    return 1.41421354f * erfinv_xla(u);
}

// ---- grid barrier (sense via generation counter), agent-scope fenced ----
__device__ __forceinline__ void gridbar(int* bar) {
    __syncthreads();
    if (threadIdx.x == 0) {
        __threadfence();   // release: drain + L2 writeback (agent scope)
        int* cnt = bar;
        int* gen = bar + 1;
        int g = __hip_atomic_load(gen, __ATOMIC_ACQUIRE, __HIP_MEMORY_SCOPE_AGENT);
        int a = __hip_atomic_fetch_add(cnt, 1, __ATOMIC_ACQ_REL, __HIP_MEMORY_SCOPE_AGENT);
        if (a == NBLK - 1) {
            __hip_atomic_store(cnt, 0, __ATOMIC_RELAXED, __HIP_MEMORY_SCOPE_AGENT);
            __hip_atomic_fetch_add(gen, 1, __ATOMIC_RELEASE, __HIP_MEMORY_SCOPE_AGENT);
        } else {
            while (__hip_atomic_load(gen, __ATOMIC_ACQUIRE, __HIP_MEMORY_SCOPE_AGENT) == g)
                __builtin_amdgcn_s_sleep(1);
        }
        __threadfence();   // acquire: invalidate stale lines before next phase's plain loads
    }
    __syncthreads();
}

// ============ the mega-kernel: sort + MLP + segment-mean + head + broadcast ============
__global__ __launch_bounds__(TPB, 2) void k_mega(
    const float* __restrict__ x, const int* __restrict__ gl,
    const float* __restrict__ W1, const float* __restrict__ b1,
    const float* __restrict__ W2, const float* __restrict__ b2,
    const float* __restrict__ W3, const float* __restrict__ b3,
    const float* __restrict__ wmu, const float* __restrict__ bmu,
    const float* __restrict__ wlv, const float* __restrict__ blv,
    float* __restrict__ out,
    float* __restrict__ gsum, int* __restrict__ counts, int* __restrict__ cursor,
    float* __restrict__ taug, float* __restrict__ ltaug,
    int2* __restrict__ spk, int* __restrict__ bar)
{
    __shared__ __align__(16) unsigned short w1t[64 * 64];    // [j][k] bf16, swizzled
    __shared__ __align__(16) unsigned short w2t[64 * 64];
    __shared__ __align__(16) unsigned short xh[NW][64 * 64]; // per-wave h1/zT; phase-F w3 alias
    __shared__ float b1s[64], b2s[64];
    __shared__ int sg_s[NW][64];

    const int t = threadIdx.x;
    const int wv = t >> 6, lane = t & 63;
    const int lj = lane & 15, lg = lane >> 4;
    const int gtid = blockIdx.x * TPB + t;       // 0 .. 131071

    // ---- stage W1^T, W2^T (bf16, swizzled) — block-local, no cross-block dep ----
    {
        const float4* W1v = (const float4*)W1;
        const float4* W2v = (const float4*)W2;
        #pragma unroll
        for (int i = 0; i < 4; ++i) {
            int e4 = i * 256 + t;
            int k  = e4 >> 4;
            int j0 = (e4 & 15) * 4;
            float4 a = W1v[e4];
            float4 b = W2v[e4];
            float av[4] = {a.x, a.y, a.z, a.w};
            float bv[4] = {b.x, b.y, b.z, b.w};
            #pragma unroll
            for (int c = 0; c < 4; ++c) {
                int j = j0 + c;
                int off = j * 128 + ((2 * k) ^ ((j & 7) << 4));
                *(unsigned short*)((char*)w1t + off) = f2bf(av[c]);
                *(unsigned short*)((char*)w2t + off) = f2bf(bv[c]);
            }
        }
        if (t < 64) { b1s[t] = b1[t]; b2s[t] = b2[t]; }
    }

    // ---- phase A: zero counts + gsum ----
    {
        if (gtid < KN / 4) ((int4*)counts)[gtid] = make_int4(0, 0, 0, 0);
        const float4 z4 = make_float4(0.f, 0.f, 0.f, 0.f);
        #pragma unroll
        for (int i = 0; i < 2; ++i) {
            int j = i * (NBLK * TPB) + gtid;
            if (j < KN * HN / 4) ((float4*)gsum)[j] = z4;
        }
    }
    gridbar(bar);

    // ---- phase B: histogram ----
    for (int i = gtid; i < BN / 4; i += NBLK * TPB) {
        int4 g = ((const int4*)gl)[i];
        atomicAdd(&counts[g.x], 1); atomicAdd(&counts[g.y], 1);
        atomicAdd(&counts[g.z], 1); atomicAdd(&counts[g.w], 1);
    }
    gridbar(bar);

    // ---- phase C: exclusive scan (block 0 only) ----
    if (blockIdx.x == 0) {
        const int4* cc4 = (const int4*)counts;
        int tsum = 0;
        #pragma unroll
        for (int i = 0; i < 16; ++i) {
            int4 q = cc4[t * 16 + i];
            tsum += q.x + q.y + q.z + q.w;
        }
        int inc = tsum;
        #pragma unroll
        for (int off = 1; off < 64; off <<= 1) {
            int v = __shfl_up(inc, off);
            if (lane >= off) inc += v;
        }
        if (lane == 63) sg_s[0][wv] = inc;      // reuse sg_s as 4-entry wave-total scratch
        __syncthreads();
        int wb = 0;
        #pragma unroll
        for (int w = 0; w < 4; ++w) wb += (w < wv) ? sg_s[0][w] : 0;
        int run = wb + inc - tsum;              // exclusive prefix for this thread's 64 counts
        int4* cu4 = (int4*)cursor;
        #pragma unroll
        for (int i = 0; i < 16; ++i) {
            int4 q = cc4[t * 16 + i];
            int4 o;
            o.x = run; o.y = run + q.x; o.z = o.y + q.y; o.w = o.z + q.z;
            run = o.w + q.w;
            cu4[t * 16 + i] = o;
        }
    }
    gridbar(bar);

    // ---- phase D: scatter ----
    for (int i = gtid; i < BN / 4; i += NBLK * TPB) {
        int4 g = ((const int4*)gl)[i];
        int r = i * 4;
        int p0 = atomicAdd(&cursor[g.x], 1); spk[p0] = make_int2(r,     g.x);
        int p1 = atomicAdd(&cursor[g.y], 1); spk[p1] = make_int2(r + 1, g.y);
        int p2 = atomicAdd(&cursor[g.z], 1); spk[p2] = make_int2(r + 2, g.z);
        int p3 = atomicAdd(&cursor[g.w], 1); spk[p3] = make_int2(r + 3, g.w);
    }
    gridbar(bar);

    // ---- phase E: pipelined MLP on sorted rows + segmented reduce (round-6 pstep) ----
    {
        float bc1[4], bc2[4];
        #pragma unroll
        for (int ct = 0; ct < 4; ++ct) { bc1[ct] = b1s[ct * 16 + lj]; bc2[ct] = b2s[ct * 16 + lj]; }

        unsigned short* myx = &xh[wv][0];
        int2   rsA[4], rsB[4];
        float4 xr[4][4];
        bf16x8 af[4][2];

        auto load_spk = [&](int c, int2 (&dst)[4]) {
            int cc = c < NCHUNK - 1 ? c : NCHUNK - 1;
            #pragma unroll
            for (int rt = 0; rt < 4; ++rt) {
                int r = cc * TPB + wv * 64 + rt * 16 + lj;
                dst[rt] = spk[r < BN ? r : BN - 1];
            }
        };
        auto load_x = [&](const int2 (&src)[4]) {
            #pragma unroll
            for (int rt = 0; rt < 4; ++rt) {
                const float* xp = x + (size_t)src[rt].x * 64 + lg * 8;
                xr[rt][0] = *(const float4*)(xp);
                xr[rt][1] = *(const float4*)(xp + 4);
                xr[rt][2] = *(const float4*)(xp + 32);
                xr[rt][3] = *(const float4*)(xp + 36);
            }
        };
        auto compute = [&]() {
            f32x4 acc[4][4];
            #pragma unroll
            for (int a = 0; a < 4; ++a)
                #pragma unroll
                for (int b = 0; b < 4; ++b) acc[a][b] = f32x4{0.f, 0.f, 0.f, 0.f};
            #pragma unroll
            for (int kk = 0; kk < 2; ++kk) {
                const int kbyte = kk * 64 + lg * 16;
                bf16x8 bw[4];
                #pragma unroll
                for (int ct = 0; ct < 4; ++ct) {
                    int row = ct * 16 + lj;
                    bw[ct] = *(const bf16x8*)((char*)w1t + row * 128 + (kbyte ^ ((row & 7) << 4)));
                }
                #pragma unroll
                for (int rt = 0; rt < 4; ++rt)
                    #pragma unroll
                    for (int ct = 0; ct < 4; ++ct)
                        acc[rt][ct] = mfma16(af[rt][kk], bw[ct], acc[rt][ct]);
            }
            #pragma unroll
            for (int rt = 0; rt < 4; ++rt) {
                #pragma unroll
                for (int ct = 0; ct < 4; ++ct) {
                    f32x4 v = acc[rt][ct];
                    #pragma unroll
                    for (int rg = 0; rg < 4; ++rg) {
                        int row = rt * 16 + lg * 4 + rg;
                        int col = ct * 16 + lj;
                        float h = silu_f(v[rg] + bc1[ct]);
                        int off = row * 128 + ((2 * col) ^ ((row & 7) << 4));
                        *(unsigned short*)((char*)myx + off) = f2bf(h);
                    }
                    acc[rt][ct] = f32x4{0.f, 0.f, 0.f, 0.f};
                }
            }
            #pragma unroll
            for (int kk = 0; kk < 2; ++kk) {
                const int kbyte = kk * 64 + lg * 16;
                bf16x8 bw[4];
                #pragma unroll
                for (int ct = 0; ct < 4; ++ct) {
                    int row = ct * 16 + lj;
                    bw[ct] = *(const bf16x8*)((char*)w2t + row * 128 + (kbyte ^ ((row & 7) << 4)));
                }
                #pragma unroll
                for (int rt = 0; rt < 4; ++rt) {
                    int row = rt * 16 + lj;
                    bf16x8 aw = *(const bf16x8*)((char*)myx + row * 128 + (kbyte ^ ((row & 7) << 4)));
                    #pragma unroll
                    for (int ct = 0; ct < 4; ++ct)
                        acc[rt][ct] = mfma16(aw, bw[ct], acc[rt][ct]);
                }
            }
            #pragma unroll
            for (int rt = 0; rt < 4; ++rt) {
                #pragma unroll
                for (int ct = 0; ct < 4; ++ct) {
                    f32x4 v = acc[rt][ct];
                    int col  = ct * 16 + lj;
                    int row0 = rt * 16 + lg * 4;
                    ushort4 pk;
                    pk.x = f2bf(silu_f(v[0] + bc2[ct]));
                    pk.y = f2bf(silu_f(v[1] + bc2[ct]));
                    pk.z = f2bf(silu_f(v[2] + bc2[ct]));
                    pk.w = f2bf(silu_f(v[3] + bc2[ct]));
                    *(ushort4*)((char*)myx + col * 128 + ((2 * row0) ^ ((col & 7) << 4))) = pk;
                }
            }
            {
                const int c2 = lane;
                const char* zT = (const char*)myx;
                float vsum = 0.0f;
                int curg = -2;
                #pragma unroll
                for (int blk = 0; blk < 8; ++blk) {
                    u16x8 v = *(const u16x8*)(zT + c2 * 128 + ((16 * blk) ^ ((c2 & 7) << 4)));
                    int4 ga = *(const int4*)(&sg_s[wv][blk * 8]);
                    int4 gb = *(const int4*)(&sg_s[wv][blk * 8 + 4]);
                    int gs[8] = {ga.x, ga.y, ga.z, ga.w, gb.x, gb.y, gb.z, gb.w};
                    #pragma unroll
                    for (int j = 0; j < 8; ++j) {
                        int g = gs[j];
                        if (g != curg) {
                            if (curg >= 0) atomicAdd(&gsum[curg * 64 + c2], vsum);
                            vsum = 0.0f;
                            curg = g;
                        }
                        vsum += bf2f(v[j]);
                    }
                }
                if (curg >= 0) atomicAdd(&gsum[curg * 64 + c2], vsum);
            }
        };
        auto pstep = [&](int2 (&CUR)[4], int2 (&NXT)[4], int c) {
            if (lg == 0) {
                #pragma unroll
                for (int rt = 0; rt < 4; ++rt) {
                    int r = c * TPB + wv * 64 + rt * 16 + lj;
                    sg_s[wv][rt * 16 + lj] = (r < BN) ? CUR[rt].y : -1;
                }
            }
            #pragma unroll
            for (int rt = 0; rt < 4; ++rt)
                #pragma unroll
                for (int kk = 0; kk < 2; ++kk) {
                    float4 a = xr[rt][kk * 2], b = xr[rt][kk * 2 + 1];
                    u16x8 u;
                    u[0] = f2bf(a.x); u[1] = f2bf(a.y); u[2] = f2bf(a.z); u[3] = f2bf(a.w);
                    u[4] = f2bf(b.x); u[5] = f2bf(b.y); u[6] = f2bf(b.z); u[7] = f2bf(b.w);
                    af[rt][kk] = __builtin_bit_cast(bf16x8, u);
                }
            load_x(NXT);                 // gather chunk c+NBLK
            load_spk(c + 2 * NBLK, CUR); // addresses for chunk c+2*NBLK
            compute();
        };

        const int c0 = blockIdx.x;
        load_spk(c0, rsA);
        load_spk(c0 + NBLK, rsB);
        load_x(rsA);
        int c = c0;
        while (true) {
            pstep(rsA, rsB, c); c += NBLK; if (c >= NCHUNK) break;
            pstep(rsB, rsA, c); c += NBLK; if (c >= NCHUNK) break;
        }
    }
    gridbar(bar);

    // ---- phase F: group head + reparam sample (blocks 0..63; w3 aliased onto xh) ----
    if (blockIdx.x < KN / TPB) {
        float* w3f = (float*)&xh[0][0];          // 16 KB alias
        const int j = t & 63, q = t >> 6;
        #pragma unroll
        for (int i = 0; i < 16; ++i) {
            int k = q * 16 + i;
            w3f[j * 64 + k] = W3[k * 64 + j];    // coalesced read, transposed write
        }
        __syncthreads();

        const int gid = blockIdx.x * TPB + t;
        const float inv = 1.0f / (float)counts[gid];
        float gf[64];
        #pragma unroll
        for (int i = 0; i < 16; ++i) {
            float4 v = *(const float4*)(gsum + (size_t)gid * 64 + i * 4);
            gf[i * 4 + 0] = v.x * inv; gf[i * 4 + 1] = v.y * inv;
            gf[i * 4 + 2] = v.z * inv; gf[i * 4 + 3] = v.w * inv;
        }
        float mu = bmu[0], lv = blv[0];
        for (int jj = 0; jj < 64; ++jj) {
            float a = b3[jj];
            const float4* wr = (const float4*)(w3f + jj * 64);
            #pragma unroll
            for (int k = 0; k < 16; ++k) {
                float4 wvv = wr[k];
                a += gf[k * 4 + 0] * wvv.x + gf[k * 4 + 1] * wvv.y
                   + gf[k * 4 + 2] * wvv.z + gf[k * 4 + 3] * wvv.w;
            }
            float h = silu_f(a);
            mu += h * wmu[jj];
            lv += h * wlv[jj];
        }
        lv = fminf(fmaxf(lv, -10.0f), 4.0f);
        float sd  = __expf(0.5f * lv);
        float eps = jax_eps16384(gid);
        float lt  = mu + sd * eps;
        out[gid]      = mu;
        out[KN + gid] = lv;
        taug[gid]  = __expf(lt);
        ltaug[gid] = lt;
    }
    gridbar(bar);

    // ---- phase G: broadcast per-group sample to reflections ----
    for (int i = gtid; i < BN / 4; i += NBLK * TPB) {
        int4 g = ((const int4*)gl)[i];
        float4 tv = make_float4(taug[g.x],  taug[g.y],  taug[g.z],  taug[g.w]);
        float4 lv = make_float4(ltaug[g.x], ltaug[g.y], ltaug[g.z], ltaug[g.w]);
        ((float4*)(out + 2 * KN))[i]      = tv;
        ((float4*)(out + 2 * KN + BN))[i] = lv;
    }
}

extern "C" void kernel_launch(void* const* d_in, const int* in_sizes, int n_in,
                              void* d_out, int out_size, void* d_ws, size_t ws_size,
                              hipStream_t stream)
{
    const float* x   = (const float*)d_in[0];
    const int*   gl  = (const int*)d_in[1];
    const float* W1  = (const float*)d_in[2];
    const float* b1  = (const float*)d_in[3];
    const float* W2  = (const float*)d_in[4];
    const float* b2  = (const float*)d_in[5];
    const float* W3  = (const float*)d_in[6];
    const float* b3  = (const float*)d_in[7];
    const float* wmu = (const float*)d_in[8];
    const float* bmu = (const float*)d_in[9];
    const float* wlv = (const float*)d_in[10];
    const float* blv = (const float*)d_in[11];
    float* out = (float*)d_out;

    float* ws     = (float*)d_ws;
    float* gsum   = ws;                          // KN*HN f32
    int*   counts = (int*)(gsum + KN * HN);      // KN
    int*   cursor = counts + KN;                 // KN
    float* taug   = (float*)(cursor + KN);       // KN
    float* ltaug  = taug + KN;                   // KN
    int2*  spk    = (int2*)(ltaug + KN);         // BN int2
    int*   bar    = (int*)(spk + BN);            // 2 ints: {counter, generation}

    hipMemsetAsync(bar, 0, 2 * sizeof(int), stream);
    k_mega<<<NBLK, TPB, 0, stream>>>(x, gl, W1, b1, W2, b2, W3, b3, wmu, bmu, wlv, blv,
                                     out, gsum, counts, cursor, taug, ltaug, spk, bar);
}

// Round 9
// 233.900 us; speedup vs baseline: 3.0796x; 3.0796x over previous
//
#include <hip/hip_runtime.h>

#define BN 1000000
#define KN 16384
#define HN 64
#define TPB 512
#define NW  8
#define CHROWS 256                      // rows per block-chunk (8 waves x 32 rows)
#define NB  512                         // persistent grid: 2 blocks/CU
#define NCHUNK ((BN + CHROWS - 1) / CHROWS) // 3907

typedef __bf16 bf16x8 __attribute__((ext_vector_type(8)));
typedef float  f32x4  __attribute__((ext_vector_type(4)));
typedef unsigned short u16x8 __attribute__((ext_vector_type(8)));

__device__ __forceinline__ unsigned short f2bf(float f) {
    return __builtin_bit_cast(unsigned short, (__bf16)f);   // HW v_cvt (RTNE)
}
__device__ __forceinline__ float bf2f(unsigned short b) {
    return (float)__builtin_bit_cast(__bf16, b);
}
__device__ __forceinline__ float silu_f(float v) {
    return v * __builtin_amdgcn_rcpf(1.0f + __expf(-v));
}
__device__ __forceinline__ f32x4 mfma16(bf16x8 a, bf16x8 b, f32x4 c) {
    return __builtin_amdgcn_mfma_f32_16x16x32_bf16(a, b, c, 0, 0, 0);
}

// ---- XLA ErfInv32 polynomial ----
__device__ __forceinline__ float erfinv_xla(float x) {
    float w = -log1pf(-x * x);
    float p;
    if (w < 5.0f) {
        w -= 2.5f;
        p = 2.81022636e-08f;
        p = fmaf(p, w, 3.43273939e-07f);
        p = fmaf(p, w, -3.5233877e-06f);
        p = fmaf(p, w, -4.39150654e-06f);
        p = fmaf(p, w, 0.00021858087f);
        p = fmaf(p, w, -0.00125372503f);
        p = fmaf(p, w, -0.00417768164f);
        p = fmaf(p, w, 0.246640727f);
        p = fmaf(p, w, 1.50140941f);
    } else {
        w = sqrtf(w) - 3.0f;
        p = -0.000200214257f;
        p = fmaf(p, w, 0.000100950558f);
        p = fmaf(p, w, 0.00134934322f);
        p = fmaf(p, w, -0.00367342844f);
        p = fmaf(p, w, 0.00573950773f);
        p = fmaf(p, w, -0.0076224613f);
        p = fmaf(p, w, 0.00943887047f);
        p = fmaf(p, w, 1.00167406f);
        p = fmaf(p, w, 2.83297682f);
    }
    return p * x;
}

// ---- jax.random.normal(key(42), (16384,)), threefry_partitionable: bits = out0^out1 ----
__device__ __forceinline__ float jax_eps16384(int gid) {
    const unsigned k0 = 0u, k1 = 42u, k2 = 0x1BD11BDAu ^ 0u ^ 42u;
    unsigned x0 = 0u + k0;
    unsigned x1 = (unsigned)gid + k1;
#define TF_RND(r) { x0 += x1; x1 = (x1 << (r)) | (x1 >> (32 - (r))); x1 ^= x0; }
    TF_RND(13) TF_RND(15) TF_RND(26) TF_RND(6)  x0 += k1; x1 += k2 + 1u;
    TF_RND(17) TF_RND(29) TF_RND(16) TF_RND(24) x0 += k2; x1 += k0 + 2u;
    TF_RND(13) TF_RND(15) TF_RND(26) TF_RND(6)  x0 += k0; x1 += k1 + 3u;
    TF_RND(17) TF_RND(29) TF_RND(16) TF_RND(24) x0 += k1; x1 += k2 + 4u;
    TF_RND(13) TF_RND(15) TF_RND(26) TF_RND(6)  x0 += k2; x1 += k0 + 5u;
#undef TF_RND
    unsigned bits = x0 ^ x1;
    float f = __uint_as_float((bits >> 9) | 0x3f800000u) - 1.0f;
    const float mn = -0.99999994f;
    float u = fmaxf(f * 2.0f + mn, mn);
    return 1.41421354f * erfinv_xla(u);
}

// ============ counting sort: histogram(+gsum zero), shuffle-scan, scatter ============
__global__ __launch_bounds__(256) void k_count(const int* __restrict__ gl,
                                               int* __restrict__ counts,
                                               float4* __restrict__ gz) {
    int i = blockIdx.x * 256 + threadIdx.x;
    const float4 z4 = make_float4(0.f, 0.f, 0.f, 0.f);
    for (int j = i; j < KN * HN / 4; j += 250112) gz[j] = z4;   // fold gsum memset in
    if (i < BN / 4) {
        int4 g = ((const int4*)gl)[i];
        atomicAdd(&counts[g.x], 1); atomicAdd(&counts[g.y], 1);
        atomicAdd(&counts[g.z], 1); atomicAdd(&counts[g.w], 1);
    }
}

__global__ __launch_bounds__(1024) void k_scan(const int* __restrict__ counts, int* __restrict__ cursor) {
    __shared__ int wtot[16];
    const int t = threadIdx.x, lane = t & 63, wv = t >> 6;
    const int4* c4 = (const int4*)counts;
    int4 q0 = c4[t * 4], q1 = c4[t * 4 + 1], q2 = c4[t * 4 + 2], q3 = c4[t * 4 + 3];
    int c[16] = {q0.x, q0.y, q0.z, q0.w, q1.x, q1.y, q1.z, q1.w,
                 q2.x, q2.y, q2.z, q2.w, q3.x, q3.y, q3.z, q3.w};
    int loc[16], s = 0;
    #pragma unroll
    for (int i = 0; i < 16; ++i) { loc[i] = s; s += c[i]; }
    const int own = s;
    #pragma unroll
    for (int off = 1; off < 64; off <<= 1) {      // inclusive wave scan
        int v = __shfl_up(s, off);
        if (lane >= off) s += v;
    }
    if (lane == 63) wtot[wv] = s;
    __syncthreads();
    int wbase = 0;
    #pragma unroll
    for (int w = 0; w < 16; ++w) wbase += (w < wv) ? wtot[w] : 0;
    const int ebase = wbase + s - own;            // exclusive prefix of this thread
    int o[16];
    #pragma unroll
    for (int i = 0; i < 16; ++i) o[i] = ebase + loc[i];
    int4* o4 = (int4*)cursor;
    o4[t * 4]     = make_int4(o[0],  o[1],  o[2],  o[3]);
    o4[t * 4 + 1] = make_int4(o[4],  o[5],  o[6],  o[7]);
    o4[t * 4 + 2] = make_int4(o[8],  o[9],  o[10], o[11]);
    o4[t * 4 + 3] = make_int4(o[12], o[13], o[14], o[15]);
}

__global__ __launch_bounds__(256) void k_scatter(const int* __restrict__ gl, int* __restrict__ cursor,
                                                 int2* __restrict__ spk) {
    int i = blockIdx.x * 256 + threadIdx.x;
    if (i < BN / 4) {
        int4 g = ((const int4*)gl)[i];
        int r = i * 4;
        int p0 = atomicAdd(&cursor[g.x], 1); spk[p0] = make_int2(r,     g.x);
        int p1 = atomicAdd(&cursor[g.y], 1); spk[p1] = make_int2(r + 1, g.y);
        int p2 = atomicAdd(&cursor[g.z], 1); spk[p2] = make_int2(r + 2, g.z);
        int p3 = atomicAdd(&cursor[g.w], 1); spk[p3] = make_int2(r + 3, g.w);
    }
}

// ============ phase 1: persistent MLP on sorted rows + segmented reduce ============
// 32 rows/wave (xr=32 VGPR) -> 4 waves/SIMD at 128 VGPR: 2x round-6 latency overlap.
__global__ __launch_bounds__(TPB, 4) void k_phase1(
    const float* __restrict__ x, const int2* __restrict__ spk,
    const float* __restrict__ W1, const float* __restrict__ b1,
    const float* __restrict__ W2, const float* __restrict__ b2,
    float* __restrict__ gsum)
{
    __shared__ __align__(16) unsigned short w1t[64 * 64];    // [j][k] bf16, swizzled
    __shared__ __align__(16) unsigned short w2t[64 * 64];
    __shared__ __align__(16) unsigned short xh[NW][32 * 64]; // per-wave: h1 then zT (4KB)
    __shared__ float b1s[64], b2s[64];
    __shared__ int sg_s[NW][32];

    const int t = threadIdx.x;
    const int wv = t >> 6, lane = t & 63;
    const int lj = lane & 15, lg = lane >> 4;

    // ---- stage W1^T, W2^T (bf16, swizzled) — once per block ----
    {
        const float4* W1v = (const float4*)W1;
        const float4* W2v = (const float4*)W2;
        #pragma unroll
        for (int i = 0; i < 2; ++i) {
            int e4 = i * TPB + t;
            int k  = e4 >> 4;
            int j0 = (e4 & 15) * 4;
            float4 a = W1v[e4];
            float4 b = W2v[e4];
            float av[4] = {a.x, a.y, a.z, a.w};
            float bv[4] = {b.x, b.y, b.z, b.w};
            #pragma unroll
            for (int c = 0; c < 4; ++c) {
                int j = j0 + c;
                int off = j * 128 + ((2 * k) ^ ((j & 7) << 4));
                *(unsigned short*)((char*)w1t + off) = f2bf(av[c]);
                *(unsigned short*)((char*)w2t + off) = f2bf(bv[c]);
            }
        }
        if (t < 64) { b1s[t] = b1[t]; b2s[t] = b2[t]; }
    }
    __syncthreads();   // the ONLY block barrier (startup)

    float bc1[4], bc2[4];
    #pragma unroll
    for (int ct = 0; ct < 4; ++ct) { bc1[ct] = b1s[ct * 16 + lj]; bc2[ct] = b2s[ct * 16 + lj]; }

    unsigned short* myx = &xh[wv][0];
    int2 rsA[2], rsB[2];

    // helper: issue spk loads for chunk c into dst (2 rows-of-16 per wave)
    auto load_spk = [&](int c, int2 (&dst)[2]) {
        int cc = c < NCHUNK - 1 ? c : NCHUNK - 1;
        #pragma unroll
        for (int rt = 0; rt < 2; ++rt) {
            int r = cc * CHROWS + wv * 32 + rt * 16 + lj;
            dst[rt] = spk[r < BN ? r : BN - 1];
        }
    };

    // one full chunk: gather (stalls on CUR), prefetch spk(c+NB) into NXT, compute
    auto iter = [&](int2 (&CUR)[2], int2 (&NXT)[2], int c) {
        // issue gathers for chunk c (addresses in CUR, already resident)
        float4 xr[2][4];
        #pragma unroll
        for (int rt = 0; rt < 2; ++rt) {
            const float* xp = x + (size_t)CUR[rt].x * 64 + lg * 8;
            xr[rt][0] = *(const float4*)(xp);
            xr[rt][1] = *(const float4*)(xp + 4);
            xr[rt][2] = *(const float4*)(xp + 32);
            xr[rt][3] = *(const float4*)(xp + 36);
        }
        // prefetch next chunk's spk
        load_spk(c + NB, NXT);
        // sg for chunk c (wave-private)
        if (lg == 0) {
            #pragma unroll
            for (int rt = 0; rt < 2; ++rt) {
                int r = c * CHROWS + wv * 32 + rt * 16 + lj;
                sg_s[wv][rt * 16 + lj] = (r < BN) ? CUR[rt].y : -1;
            }
        }
        // convert to bf16 A-fragments (waits on xr as values arrive)
        bf16x8 af[2][2];
        #pragma unroll
        for (int rt = 0; rt < 2; ++rt)
            #pragma unroll
            for (int kk = 0; kk < 2; ++kk) {
                float4 a = xr[rt][kk * 2], b = xr[rt][kk * 2 + 1];
                u16x8 u;
                u[0] = f2bf(a.x); u[1] = f2bf(a.y); u[2] = f2bf(a.z); u[3] = f2bf(a.w);
                u[4] = f2bf(b.x); u[5] = f2bf(b.y); u[6] = f2bf(b.z); u[7] = f2bf(b.w);
                af[rt][kk] = __builtin_bit_cast(bf16x8, u);
            }

        f32x4 acc[2][4];
        #pragma unroll
        for (int a = 0; a < 2; ++a)
            #pragma unroll
            for (int b = 0; b < 4; ++b) acc[a][b] = f32x4{0.f, 0.f, 0.f, 0.f};
        // layer 1 (A from regs, B from LDS)
        #pragma unroll
        for (int kk = 0; kk < 2; ++kk) {
            const int kbyte = kk * 64 + lg * 16;
            bf16x8 bw[4];
            #pragma unroll
            for (int ct = 0; ct < 4; ++ct) {
                int row = ct * 16 + lj;
                bw[ct] = *(const bf16x8*)((char*)w1t + row * 128 + (kbyte ^ ((row & 7) << 4)));
            }
            #pragma unroll
            for (int rt = 0; rt < 2; ++rt)
                #pragma unroll
                for (int ct = 0; ct < 4; ++ct)
                    acc[rt][ct] = mfma16(af[rt][kk], bw[ct], acc[rt][ct]);
        }
        // epilogue 1: h1 -> own-wave LDS (A-layout rows 0..31, swizzled)
        #pragma unroll
        for (int rt = 0; rt < 2; ++rt) {
            #pragma unroll
            for (int ct = 0; ct < 4; ++ct) {
                f32x4 v = acc[rt][ct];
                #pragma unroll
                for (int rg = 0; rg < 4; ++rg) {
                    int row = rt * 16 + lg * 4 + rg;
                    int col = ct * 16 + lj;
                    float h = silu_f(v[rg] + bc1[ct]);
                    int off = row * 128 + ((2 * col) ^ ((row & 7) << 4));
                    *(unsigned short*)((char*)myx + off) = f2bf(h);
                }
                acc[rt][ct] = f32x4{0.f, 0.f, 0.f, 0.f};
            }
        }
        // layer 2 (A from own-wave LDS, B from LDS)
        #pragma unroll
        for (int kk = 0; kk < 2; ++kk) {
            const int kbyte = kk * 64 + lg * 16;
            bf16x8 bw[4];
            #pragma unroll
            for (int ct = 0; ct < 4; ++ct) {
                int row = ct * 16 + lj;
                bw[ct] = *(const bf16x8*)((char*)w2t + row * 128 + (kbyte ^ ((row & 7) << 4)));
            }
            #pragma unroll
            for (int rt = 0; rt < 2; ++rt) {
                int row = rt * 16 + lj;
                bf16x8 aw = *(const bf16x8*)((char*)myx + row * 128 + (kbyte ^ ((row & 7) << 4)));
                #pragma unroll
                for (int ct = 0; ct < 4; ++ct)
                    acc[rt][ct] = mfma16(aw, bw[ct], acc[rt][ct]);
            }
        }
        // epilogue 2: zT col-major (col stride 64B, swizzle (col&3)<<4), packed ushort4
        #pragma unroll
        for (int rt = 0; rt < 2; ++rt) {
            #pragma unroll
            for (int ct = 0; ct < 4; ++ct) {
                f32x4 v = acc[rt][ct];
                int col  = ct * 16 + lj;
                int row0 = rt * 16 + lg * 4;
                ushort4 pk;
                pk.x = f2bf(silu_f(v[0] + bc2[ct]));
                pk.y = f2bf(silu_f(v[1] + bc2[ct]));
                pk.z = f2bf(silu_f(v[2] + bc2[ct]));
                pk.w = f2bf(silu_f(v[3] + bc2[ct]));
                *(ushort4*)((char*)myx + col * 64 + ((2 * row0) ^ ((col & 3) << 4))) = pk;
            }
        }
        // segmented reduce: lane owns col; 8 rows per ds_read_b128 (4 blocks)
        {
            const int c2 = lane;
            const char* zT = (const char*)myx;
            float vsum = 0.0f;
            int curg = -2;
            #pragma unroll
            for (int blk = 0; blk < 4; ++blk) {
                u16x8 v = *(const u16x8*)(zT + c2 * 64 + ((16 * blk) ^ ((c2 & 3) << 4)));
                int4 ga = *(const int4*)(&sg_s[wv][blk * 8]);
                int4 gb = *(const int4*)(&sg_s[wv][blk * 8 + 4]);
                int gs[8] = {ga.x, ga.y, ga.z, ga.w, gb.x, gb.y, gb.z, gb.w};
                #pragma unroll
                for (int j = 0; j < 8; ++j) {
                    int g = gs[j];
                    if (g != curg) {
                        if (curg >= 0) atomicAdd(&gsum[curg * 64 + c2], vsum);
                        vsum = 0.0f;
                        curg = g;
                    }
                    vsum += bf2f(v[j]);
                }
            }
            if (curg >= 0) atomicAdd(&gsum[curg * 64 + c2], vsum);
        }
    };

    // ---- persistent loop, 1-deep spk ping-pong ----
    int c = blockIdx.x;
    load_spk(c, rsA);
    while (true) {
        iter(rsA, rsB, c); c += NB; if (c >= NCHUNK) break;
        iter(rsB, rsA, c); c += NB; if (c >= NCHUNK) break;
    }
}

// ============ phase 2: group head + reparam sample ============
__global__ __launch_bounds__(64) void k_phase2(
    const float* __restrict__ gsum, const int* __restrict__ counts,
    const float* __restrict__ W3, const float* __restrict__ b3,
    const float* __restrict__ wmu, const float* __restrict__ bmu,
    const float* __restrict__ wlv, const float* __restrict__ blv,
    float* __restrict__ out, float* __restrict__ taug, float* __restrict__ ltaug)
{
    __shared__ __align__(16) float w3t[64 * 64];   // [j][k]
    __shared__ float b3s[64], wmus[64], wlvs[64];
    const int t = threadIdx.x;
    for (int i = 0; i < 64; ++i) w3t[t * 64 + i] = W3[i * 64 + t];
    b3s[t] = b3[t]; wmus[t] = wmu[t]; wlvs[t] = wlv[t];
    __syncthreads();

    const int gid = blockIdx.x * 64 + t;
    const float inv = 1.0f / (float)counts[gid];
    float gf[64];
    #pragma unroll
    for (int i = 0; i < 16; ++i) {
        float4 v = *(const float4*)(gsum + (size_t)gid * 64 + i * 4);
        gf[i * 4 + 0] = v.x * inv; gf[i * 4 + 1] = v.y * inv;
        gf[i * 4 + 2] = v.z * inv; gf[i * 4 + 3] = v.w * inv;
    }
    float mu = bmu[0], lv = blv[0];
    for (int j = 0; j < 64; ++j) {
        float a = b3s[j];
        const float4* wr = (const float4*)(w3t + j * 64);
        #pragma unroll
        for (int k = 0; k < 16; ++k) {
            float4 wv = wr[k];
            a += gf[k * 4 + 0] * wv.x + gf[k * 4 + 1] * wv.y
               + gf[k * 4 + 2] * wv.z + gf[k * 4 + 3] * wv.w;
        }
        float h = silu_f(a);
        mu += h * wmus[j];
        lv += h * wlvs[j];
    }
    lv = fminf(fmaxf(lv, -10.0f), 4.0f);
    float sd  = __expf(0.5f * lv);
    float eps = jax_eps16384(gid);
    float lt  = mu + sd * eps;
    out[gid]      = mu;
    out[KN + gid] = lv;
    taug[gid]  = __expf(lt);
    ltaug[gid] = lt;
}

// ============ phase 3: broadcast per-group sample to reflections ============
__global__ __launch_bounds__(256) void k_phase3(
    const int* __restrict__ gl, const float* __restrict__ taug,
    const float* __restrict__ ltaug, float* __restrict__ out)
{
    int i = blockIdx.x * 256 + threadIdx.x;
    if (i < BN / 4) {
        int4 g = ((const int4*)gl)[i];
        float4 tv = make_float4(taug[g.x],  taug[g.y],  taug[g.z],  taug[g.w]);
        float4 lv = make_float4(ltaug[g.x], ltaug[g.y], ltaug[g.z], ltaug[g.w]);
        ((float4*)(out + 2 * KN))[i]      = tv;
        ((float4*)(out + 2 * KN + BN))[i] = lv;
    }
}

extern "C" void kernel_launch(void* const* d_in, const int* in_sizes, int n_in,
                              void* d_out, int out_size, void* d_ws, size_t ws_size,
                              hipStream_t stream)
{
    const float* x   = (const float*)d_in[0];
    const int*   gl  = (const int*)d_in[1];
    const float* W1  = (const float*)d_in[2];
    const float* b1  = (const float*)d_in[3];
    const float* W2  = (const float*)d_in[4];
    const float* b2  = (const float*)d_in[5];
    const float* W3  = (const float*)d_in[6];
    const float* b3  = (const float*)d_in[7];
    const float* wmu = (const float*)d_in[8];
    const float* bmu = (const float*)d_in[9];
    const float* wlv = (const float*)d_in[10];
    const float* blv = (const float*)d_in[11];
    float* out = (float*)d_out;

    float* ws     = (float*)d_ws;
    float* gsum   = ws;                          // KN*HN f32
    int*   counts = (int*)(gsum + KN * HN);      // KN
    int*   cursor = counts + KN;                 // KN
    float* taug   = (float*)(cursor + KN);       // KN
    float* ltaug  = taug + KN;                   // KN
    int2*  spk    = (int2*)(ltaug + KN);         // BN int2 (.x=orig row, .y=group)

    hipMemsetAsync(counts, 0, (size_t)KN * sizeof(int), stream);

    const int nb4 = (BN / 4 + 255) / 256;        // 977
    k_count  <<<nb4, 256, 0, stream>>>(gl, counts, (float4*)gsum);
    k_scan   <<<1, 1024, 0, stream>>>(counts, cursor);
    k_scatter<<<nb4, 256, 0, stream>>>(gl, cursor, spk);
    k_phase1 <<<NB, TPB, 0, stream>>>(x, spk, W1, b1, W2, b2, gsum);
    k_phase2 <<<KN / 64, 64, 0, stream>>>(gsum, counts, W3, b3, wmu, bmu, wlv, blv, out, taug, ltaug);
    k_phase3 <<<nb4, 256, 0, stream>>>(gl, taug, ltaug, out);
}